// Round 1
// baseline (1157.265 us; speedup 1.0000x reference)
//
#include <hip/hip_runtime.h>
#include <math.h>

#define N_NODES   100000
#define N_EDGES   1000000
#define N_GRAPHS  256
#define NUM_TYPES 200
#define EMB       64
#define HID       32

// ---------------- kernels ----------------

__global__ void k_fill(float* __restrict__ p, float v, int n) {
    int i = blockIdx.x * blockDim.x + threadIdx.x;
    if (i < n) p[i] = v;
}

// table[t][j] = sum_k emb[t][k] * W1[k][j]   (200 x 32)
__global__ void k_table(const float* __restrict__ emb, const float* __restrict__ W1,
                        float* __restrict__ table) {
    int i = blockIdx.x * blockDim.x + threadIdx.x;
    if (i >= NUM_TYPES * HID) return;
    int t = i / HID, j = i % HID;
    float s = 0.f;
    for (int k = 0; k < EMB; ++k) s = fmaf(emb[t * EMB + k], W1[k * HID + j], s);
    table[i] = s;
}

// deg[dst] += 1 over edges (deg pre-filled with 1.0 for self-loops)
__global__ void k_count(const int* __restrict__ dst, float* __restrict__ deg) {
    int e = blockIdx.x * blockDim.x + threadIdx.x;
    if (e < N_EDGES) atomicAdd(&deg[dst[e]], 1.0f);
}

__global__ void k_dinv(float* __restrict__ deg) {
    int i = blockIdx.x * blockDim.x + threadIdx.x;
    if (i < N_NODES) deg[i] = rsqrtf(deg[i]);   // deg >= 1 always (self-loop)
}

// y[i] = table[ids[i]] * dinv[i]; acc init = y (self-loop term)
__global__ void k_y1(const int* __restrict__ ids, const float* __restrict__ table,
                     const float* __restrict__ dinv,
                     float4* __restrict__ Y, float4* __restrict__ ACC) {
    int t = blockIdx.x * blockDim.x + threadIdx.x;
    if (t >= N_NODES * 8) return;
    int i = t >> 3, p = t & 7;
    float d = dinv[i];
    int id = ids[i];
    float4 v = ((const float4*)table)[id * 8 + p];
    v.x *= d; v.y *= d; v.z *= d; v.w *= d;
    Y[i * 8 + p] = v;
    ACC[i * 8 + p] = v;
}

// acc[dst] += y[src]  (8 lanes per edge, float4 each)
__global__ void k_scatter(const int* __restrict__ src, const int* __restrict__ dst,
                          const float4* __restrict__ Y, float* __restrict__ ACC) {
    long long t = (long long)blockIdx.x * blockDim.x + threadIdx.x;
    if (t >= (long long)N_EDGES * 8) return;
    int e = (int)(t >> 3), p = (int)(t & 7);
    int s = src[e], d = dst[e];
    float4 v = Y[s * 8 + p];
    float* a = ACC + (size_t)d * HID + p * 4;
    atomicAdd(a + 0, v.x);
    atomicAdd(a + 1, v.y);
    atomicAdd(a + 2, v.z);
    atomicAdd(a + 3, v.w);
}

// H[i] = relu(dinv[i] * acc[i] + b)
__global__ void k_h(const float4* __restrict__ ACC, const float* __restrict__ dinv,
                    const float* __restrict__ b, float4* __restrict__ H) {
    int t = blockIdx.x * blockDim.x + threadIdx.x;
    if (t >= N_NODES * 8) return;
    int i = t >> 3, p = t & 7;
    float d = dinv[i];
    float4 a = ACC[i * 8 + p];
    float4 bb = ((const float4*)b)[p];
    float4 h;
    h.x = fmaxf(fmaf(d, a.x, bb.x), 0.f);
    h.y = fmaxf(fmaf(d, a.y, bb.y), 0.f);
    h.z = fmaxf(fmaf(d, a.z, bb.z), 0.f);
    h.w = fmaxf(fmaf(d, a.w, bb.w), 0.f);
    H[i * 8 + p] = h;
}

// y[i] = (H[i] @ W2) * dinv[i]; acc init = y   (one node per thread, W2 in LDS)
__global__ __launch_bounds__(256) void k_y2(const float* __restrict__ H,
                                            const float* __restrict__ W2,
                                            const float* __restrict__ dinv,
                                            float* __restrict__ Y, float* __restrict__ ACC) {
    __shared__ float w[HID * HID];
    for (int k = threadIdx.x; k < HID * HID; k += blockDim.x) w[k] = W2[k];
    __syncthreads();
    int i = blockIdx.x * blockDim.x + threadIdx.x;
    if (i >= N_NODES) return;
    float h[HID];
    const float4* hp = (const float4*)(H + (size_t)i * HID);
    for (int q = 0; q < 8; ++q) {
        float4 v = hp[q];
        h[q * 4 + 0] = v.x; h[q * 4 + 1] = v.y; h[q * 4 + 2] = v.z; h[q * 4 + 3] = v.w;
    }
    float out[HID];
#pragma unroll
    for (int j = 0; j < HID; ++j) out[j] = 0.f;
    for (int k = 0; k < HID; ++k) {
        float hk = h[k];
#pragma unroll
        for (int j = 0; j < HID; ++j) out[j] = fmaf(hk, w[k * HID + j], out[j]);
    }
    float d = dinv[i];
    float4* yp = (float4*)(Y + (size_t)i * HID);
    float4* ap = (float4*)(ACC + (size_t)i * HID);
    for (int q = 0; q < 8; ++q) {
        float4 v;
        v.x = out[q * 4 + 0] * d; v.y = out[q * 4 + 1] * d;
        v.z = out[q * 4 + 2] * d; v.w = out[q * 4 + 3] * d;
        yp[q] = v;
        ap[q] = v;
    }
}

// pooled[batch[i]] += H[i]; counts[batch[i]] += 1
__global__ void k_pool(const float4* __restrict__ H, const int* __restrict__ batch,
                       float* __restrict__ pooled, float* __restrict__ counts) {
    int t = blockIdx.x * blockDim.x + threadIdx.x;
    if (t >= N_NODES * 8) return;
    int i = t >> 3, p = t & 7;
    int g = batch[i];
    float4 v = H[i * 8 + p];
    float* pp = pooled + (size_t)g * HID + p * 4;
    atomicAdd(pp + 0, v.x);
    atomicAdd(pp + 1, v.y);
    atomicAdd(pp + 2, v.z);
    atomicAdd(pp + 3, v.w);
    if (p == 0) atomicAdd(&counts[g], 1.0f);
}

// head: mean -> relu(@Wc1+bc1) -> sigmoid(@Wc2+bc2); one thread per graph
__global__ void k_head(const float* __restrict__ pooled, const float* __restrict__ counts,
                       const float* __restrict__ Wc1, const float* __restrict__ bc1,
                       const float* __restrict__ Wc2, const float* __restrict__ bc2,
                       float* __restrict__ out) {
    int g = blockIdx.x * blockDim.x + threadIdx.x;
    if (g >= N_GRAPHS) return;
    float inv = 1.0f / fmaxf(counts[g], 1.0f);
    float m[HID];
    for (int j = 0; j < HID; ++j) m[j] = pooled[g * HID + j] * inv;
    float hc[16];
    for (int j = 0; j < 16; ++j) {
        float s = bc1[j];
        for (int k = 0; k < HID; ++k) s = fmaf(m[k], Wc1[k * 16 + j], s);
        hc[j] = fmaxf(s, 0.f);
    }
    float s = bc2[0];
    for (int k = 0; k < 16; ++k) s = fmaf(hc[k], Wc2[k], s);
    out[g] = 1.0f / (1.0f + expf(-s));
}

// ---------------- launch ----------------

extern "C" void kernel_launch(void* const* d_in, const int* in_sizes, int n_in,
                              void* d_out, int out_size, void* d_ws, size_t ws_size,
                              hipStream_t stream) {
    const int*   ids  = (const int*)d_in[0];          // (100000,)
    const int*   src  = (const int*)d_in[1];          // edge_index[0]
    const int*   dst  = ((const int*)d_in[1]) + N_EDGES; // edge_index[1]
    const int*   batch = (const int*)d_in[2];
    const float* emb  = (const float*)d_in[3];
    const float* W1   = (const float*)d_in[4];
    const float* b1   = (const float*)d_in[5];
    const float* W2   = (const float*)d_in[6];
    const float* b2   = (const float*)d_in[7];
    const float* Wc1  = (const float*)d_in[8];
    const float* bc1  = (const float*)d_in[9];
    const float* Wc2  = (const float*)d_in[10];
    const float* bc2  = (const float*)d_in[11];
    float* out = (float*)d_out;

    // workspace layout (floats)
    float* ws = (float*)d_ws;
    float* dinv   = ws;                       // 100000
    float* table  = dinv + N_NODES;           // 6400
    float* Y      = table + NUM_TYPES * HID;  // 3.2M
    float* ACC    = Y + (size_t)N_NODES * HID;
    float* H      = ACC + (size_t)N_NODES * HID;
    float* pooled = H + (size_t)N_NODES * HID; // 8192
    float* counts = pooled + N_GRAPHS * HID;   // 256

    const int B = 256;
    const int gNodes  = (N_NODES + B - 1) / B;
    const int gNode8  = (N_NODES * 8 + B - 1) / B;
    const int gEdges  = (N_EDGES + B - 1) / B;
    const int gEdge8  = (int)(((long long)N_EDGES * 8 + B - 1) / B);

    // degree -> dinv
    k_fill<<<gNodes, B, 0, stream>>>(dinv, 1.0f, N_NODES);
    k_table<<<(NUM_TYPES * HID + B - 1) / B, B, 0, stream>>>(emb, W1, table);
    k_count<<<gEdges, B, 0, stream>>>(dst, dinv);
    k_dinv<<<gNodes, B, 0, stream>>>(dinv);

    // layer 1
    k_y1<<<gNode8, B, 0, stream>>>(ids, table, dinv, (float4*)Y, (float4*)ACC);
    k_scatter<<<gEdge8, B, 0, stream>>>(src, dst, (const float4*)Y, ACC);
    k_h<<<gNode8, B, 0, stream>>>((const float4*)ACC, dinv, b1, (float4*)H);

    // layer 2
    k_y2<<<gNodes, B, 0, stream>>>(H, W2, dinv, Y, ACC);
    k_scatter<<<gEdge8, B, 0, stream>>>(src, dst, (const float4*)Y, ACC);
    k_h<<<gNode8, B, 0, stream>>>((const float4*)ACC, dinv, b2, (float4*)H);

    // pooling + head
    k_fill<<<(N_GRAPHS * HID + N_GRAPHS + B - 1) / B, B, 0, stream>>>(pooled, 0.0f,
                                                                      N_GRAPHS * HID + N_GRAPHS);
    k_pool<<<gNode8, B, 0, stream>>>((const float4*)H, batch, pooled, counts);
    k_head<<<1, N_GRAPHS, 0, stream>>>(pooled, counts, Wc1, bc1, Wc2, bc2, out);
}

// Round 2
// 505.787 us; speedup vs baseline: 2.2880x; 2.2880x over previous
//
#include <hip/hip_runtime.h>
#include <math.h>

#define N_NODES   100000
#define N_EDGES   1000000
#define N_GRAPHS  256
#define NUM_TYPES 200
#define EMB       64
#define HID       32
#define SCAN_BLK  1024
#define NSCAN     ((N_NODES + SCAN_BLK - 1) / SCAN_BLK)   // 98 blocks

// ---------------- CSR build ----------------

__global__ void k_hist(const int* __restrict__ dst, int* __restrict__ deg) {
    int e = blockIdx.x * blockDim.x + threadIdx.x;
    if (e < N_EDGES) atomicAdd(&deg[dst[e]], 1);
}

__global__ __launch_bounds__(256) void k_scan_bsum(const int* __restrict__ deg,
                                                   int* __restrict__ bsum) {
    __shared__ int s[256];
    int tid = threadIdx.x;
    int base = blockIdx.x * SCAN_BLK + tid * 4;
    int t = 0;
    for (int j = 0; j < 4; ++j) { int i = base + j; if (i < N_NODES) t += deg[i]; }
    s[tid] = t; __syncthreads();
    for (int off = 128; off > 0; off >>= 1) {
        if (tid < off) s[tid] += s[tid + off];
        __syncthreads();
    }
    if (tid == 0) bsum[blockIdx.x] = s[0];
}

__global__ void k_scan_top(int* __restrict__ bsum) {
    if (threadIdx.x == 0) {
        int acc = 0;
        for (int b = 0; b < NSCAN; ++b) { int v = bsum[b]; bsum[b] = acc; acc += v; }
    }
}

// exclusive scan -> row_ptr & cursor; also dinv = rsqrt(deg+1)  (self-loop)
__global__ __launch_bounds__(256) void k_scan_out(const int* __restrict__ deg,
                                                  const int* __restrict__ bsum,
                                                  int* __restrict__ row_ptr,
                                                  int* __restrict__ cursor,
                                                  float* __restrict__ dinv) {
    __shared__ int s[256];
    int tid = threadIdx.x;
    int base = blockIdx.x * SCAN_BLK + tid * 4;
    int v[4]; int t = 0;
    for (int j = 0; j < 4; ++j) { int i = base + j; v[j] = (i < N_NODES) ? deg[i] : 0; t += v[j]; }
    s[tid] = t; __syncthreads();
    if (tid == 0) { int acc = 0; for (int k = 0; k < 256; ++k) { int tv = s[k]; s[k] = acc; acc += tv; } }
    __syncthreads();
    int off = bsum[blockIdx.x] + s[tid];
    for (int j = 0; j < 4; ++j) {
        int i = base + j;
        if (i < N_NODES) {
            row_ptr[i] = off; cursor[i] = off; off += v[j];
            dinv[i] = rsqrtf((float)v[j] + 1.0f);
        }
    }
}

__global__ void k_sortsrc(const int* __restrict__ src, const int* __restrict__ dst,
                          int* __restrict__ cursor, int* __restrict__ sorted_src) {
    int e = blockIdx.x * blockDim.x + threadIdx.x;
    if (e >= N_EDGES) return;
    int pos = atomicAdd(&cursor[dst[e]], 1);
    sorted_src[pos] = src[e];
}

// ---------------- feature pipeline ----------------

// table[t][j] = sum_k emb[t][k] * W1[k][j]   (200 x 32)
__global__ void k_table(const float* __restrict__ emb, const float* __restrict__ W1,
                        float* __restrict__ table) {
    int i = blockIdx.x * blockDim.x + threadIdx.x;
    if (i >= NUM_TYPES * HID) return;
    int t = i / HID, j = i % HID;
    float s = 0.f;
    for (int k = 0; k < EMB; ++k) s = fmaf(emb[t * EMB + k], W1[k * HID + j], s);
    table[i] = s;
}

// Y[i] = table[ids[i]] * dinv[i]
__global__ void k_y1(const int* __restrict__ ids, const float* __restrict__ table,
                     const float* __restrict__ dinv, float4* __restrict__ Y) {
    int t = blockIdx.x * blockDim.x + threadIdx.x;
    if (t >= N_NODES * 8) return;
    int i = t >> 3, p = t & 7;
    float d = dinv[i];
    int id = ids[i];
    float4 v = ((const float4*)table)[id * 8 + p];
    v.x *= d; v.y *= d; v.z *= d; v.w *= d;
    Y[i * 8 + p] = v;
}

// H[i] = relu(dinv[i] * (Y[i] + sum_{s->i} Y[s]) + b)   -- 8 lanes per node
__global__ void k_gather(const float4* __restrict__ Y, const int* __restrict__ row_ptr,
                         const int* __restrict__ deg, const int* __restrict__ sorted_src,
                         const float* __restrict__ dinv, const float* __restrict__ b,
                         float4* __restrict__ H) {
    int t = blockIdx.x * blockDim.x + threadIdx.x;
    if (t >= N_NODES * 8) return;
    int i = t >> 3, p = t & 7;
    float4 acc = Y[i * 8 + p];                 // self-loop term
    int s0 = row_ptr[i], n = deg[i];
    for (int e = 0; e < n; ++e) {
        int s = sorted_src[s0 + e];
        float4 v = Y[s * 8 + p];
        acc.x += v.x; acc.y += v.y; acc.z += v.z; acc.w += v.w;
    }
    float d = dinv[i];
    float4 bb = ((const float4*)b)[p];
    float4 h;
    h.x = fmaxf(fmaf(d, acc.x, bb.x), 0.f);
    h.y = fmaxf(fmaf(d, acc.y, bb.y), 0.f);
    h.z = fmaxf(fmaf(d, acc.z, bb.z), 0.f);
    h.w = fmaxf(fmaf(d, acc.w, bb.w), 0.f);
    H[i * 8 + p] = h;
}

// Y[i] = (H[i] @ W2) * dinv[i]   (one node per thread, W2 in LDS)
__global__ __launch_bounds__(256) void k_y2(const float* __restrict__ H,
                                            const float* __restrict__ W2,
                                            const float* __restrict__ dinv,
                                            float* __restrict__ Y) {
    __shared__ float w[HID * HID];
    for (int k = threadIdx.x; k < HID * HID; k += blockDim.x) w[k] = W2[k];
    __syncthreads();
    int i = blockIdx.x * blockDim.x + threadIdx.x;
    if (i >= N_NODES) return;
    float h[HID];
    const float4* hp = (const float4*)(H + (size_t)i * HID);
    for (int q = 0; q < 8; ++q) {
        float4 v = hp[q];
        h[q * 4 + 0] = v.x; h[q * 4 + 1] = v.y; h[q * 4 + 2] = v.z; h[q * 4 + 3] = v.w;
    }
    float out[HID];
#pragma unroll
    for (int j = 0; j < HID; ++j) out[j] = 0.f;
    for (int k = 0; k < HID; ++k) {
        float hk = h[k];
#pragma unroll
        for (int j = 0; j < HID; ++j) out[j] = fmaf(hk, w[k * HID + j], out[j]);
    }
    float d = dinv[i];
    float4* yp = (float4*)(Y + (size_t)i * HID);
    for (int q = 0; q < 8; ++q) {
        float4 v;
        v.x = out[q * 4 + 0] * d; v.y = out[q * 4 + 1] * d;
        v.z = out[q * 4 + 2] * d; v.w = out[q * 4 + 3] * d;
        yp[q] = v;
    }
}

// pooled[batch[i]] += H[i]; counts[batch[i]] += 1
__global__ void k_pool(const float4* __restrict__ H, const int* __restrict__ batch,
                       float* __restrict__ pooled, float* __restrict__ counts) {
    int t = blockIdx.x * blockDim.x + threadIdx.x;
    if (t >= N_NODES * 8) return;
    int i = t >> 3, p = t & 7;
    int g = batch[i];
    float4 v = H[i * 8 + p];
    float* pp = pooled + (size_t)g * HID + p * 4;
    atomicAdd(pp + 0, v.x);
    atomicAdd(pp + 1, v.y);
    atomicAdd(pp + 2, v.z);
    atomicAdd(pp + 3, v.w);
    if (p == 0) atomicAdd(&counts[g], 1.0f);
}

// head: mean -> relu(@Wc1+bc1) -> sigmoid(@Wc2+bc2); one thread per graph
__global__ void k_head(const float* __restrict__ pooled, const float* __restrict__ counts,
                       const float* __restrict__ Wc1, const float* __restrict__ bc1,
                       const float* __restrict__ Wc2, const float* __restrict__ bc2,
                       float* __restrict__ out) {
    int g = blockIdx.x * blockDim.x + threadIdx.x;
    if (g >= N_GRAPHS) return;
    float inv = 1.0f / fmaxf(counts[g], 1.0f);
    float m[HID];
    for (int j = 0; j < HID; ++j) m[j] = pooled[g * HID + j] * inv;
    float hc[16];
    for (int j = 0; j < 16; ++j) {
        float s = bc1[j];
        for (int k = 0; k < HID; ++k) s = fmaf(m[k], Wc1[k * 16 + j], s);
        hc[j] = fmaxf(s, 0.f);
    }
    float s = bc2[0];
    for (int k = 0; k < 16; ++k) s = fmaf(hc[k], Wc2[k], s);
    out[g] = 1.0f / (1.0f + expf(-s));
}

// ---------------- launch ----------------

extern "C" void kernel_launch(void* const* d_in, const int* in_sizes, int n_in,
                              void* d_out, int out_size, void* d_ws, size_t ws_size,
                              hipStream_t stream) {
    const int*   ids  = (const int*)d_in[0];
    const int*   src  = (const int*)d_in[1];
    const int*   dst  = ((const int*)d_in[1]) + N_EDGES;
    const int*   batch = (const int*)d_in[2];
    const float* emb  = (const float*)d_in[3];
    const float* W1   = (const float*)d_in[4];
    const float* b1   = (const float*)d_in[5];
    const float* W2   = (const float*)d_in[6];
    const float* b2   = (const float*)d_in[7];
    const float* Wc1  = (const float*)d_in[8];
    const float* bc1  = (const float*)d_in[9];
    const float* Wc2  = (const float*)d_in[10];
    const float* bc2  = (const float*)d_in[11];
    float* out = (float*)d_out;

    // workspace layout
    int* deg      = (int*)d_ws;                 // 100000
    int* row_ptr  = deg + N_NODES;              // 100000
    int* cursor   = row_ptr + N_NODES;          // 100000
    int* bsum     = cursor + N_NODES;           // 128
    int* ssrc     = bsum + 128;                 // 1,000,000
    float* dinv   = (float*)(ssrc + N_EDGES);   // 100000
    float* table  = dinv + N_NODES;             // 6400
    float* Y      = table + NUM_TYPES * HID;    // 3,200,000 (16B-aligned)
    float* H      = Y + (size_t)N_NODES * HID;  // 3,200,000
    float* pooled = H + (size_t)N_NODES * HID;  // 8192
    float* counts = pooled + N_GRAPHS * HID;    // 256

    const int B = 256;
    const int gNodes = (N_NODES + B - 1) / B;
    const int gNode8 = (N_NODES * 8 + B - 1) / B;
    const int gEdges = (N_EDGES + B - 1) / B;

    // CSR build + dinv
    hipMemsetAsync(deg, 0, N_NODES * sizeof(int), stream);
    k_hist<<<gEdges, B, 0, stream>>>(dst, deg);
    k_scan_bsum<<<NSCAN, B, 0, stream>>>(deg, bsum);
    k_scan_top<<<1, 64, 0, stream>>>(bsum);
    k_scan_out<<<NSCAN, B, 0, stream>>>(deg, bsum, row_ptr, cursor, dinv);
    k_sortsrc<<<gEdges, B, 0, stream>>>(src, dst, cursor, ssrc);

    // layer-1 table (emb @ W1, 200x32)
    k_table<<<(NUM_TYPES * HID + B - 1) / B, B, 0, stream>>>(emb, W1, table);

    // layer 1
    k_y1<<<gNode8, B, 0, stream>>>(ids, table, dinv, (float4*)Y);
    k_gather<<<gNode8, B, 0, stream>>>((const float4*)Y, row_ptr, deg, ssrc, dinv, b1, (float4*)H);

    // layer 2
    k_y2<<<gNodes, B, 0, stream>>>(H, W2, dinv, Y);
    k_gather<<<gNode8, B, 0, stream>>>((const float4*)Y, row_ptr, deg, ssrc, dinv, b2, (float4*)H);

    // pooling + head
    hipMemsetAsync(pooled, 0, (N_GRAPHS * HID + N_GRAPHS) * sizeof(float), stream);
    k_pool<<<gNode8, B, 0, stream>>>((const float4*)H, batch, pooled, counts);
    k_head<<<1, N_GRAPHS, 0, stream>>>(pooled, counts, Wc1, bc1, Wc2, bc2, out);
}

// Round 3
// 233.220 us; speedup vs baseline: 4.9621x; 2.1687x over previous
//
#include <hip/hip_runtime.h>
#include <math.h>

#define N_NODES   100000
#define N_EDGES   1000000
#define N_GRAPHS  256
#define NUM_TYPES 200
#define EMB       64
#define HID       32
#define SCAN_BLK  1024
#define NSCAN     ((N_NODES + SCAN_BLK - 1) / SCAN_BLK)   // 98 blocks

// ---------------- CSR build ----------------

__global__ void k_hist(const int* __restrict__ dst, int* __restrict__ deg) {
    int e = blockIdx.x * blockDim.x + threadIdx.x;
    if (e < N_EDGES) atomicAdd(&deg[dst[e]], 1);
}

__global__ __launch_bounds__(256) void k_scan_bsum(const int* __restrict__ deg,
                                                   int* __restrict__ bsum) {
    __shared__ int s[256];
    int tid = threadIdx.x;
    int base = blockIdx.x * SCAN_BLK + tid * 4;
    int t = 0;
    for (int j = 0; j < 4; ++j) { int i = base + j; if (i < N_NODES) t += deg[i]; }
    s[tid] = t; __syncthreads();
    for (int off = 128; off > 0; off >>= 1) {
        if (tid < off) s[tid] += s[tid + off];
        __syncthreads();
    }
    if (tid == 0) bsum[blockIdx.x] = s[0];
}

__global__ void k_scan_top(int* __restrict__ bsum) {
    if (threadIdx.x == 0) {
        int acc = 0;
        for (int b = 0; b < NSCAN; ++b) { int v = bsum[b]; bsum[b] = acc; acc += v; }
    }
}

// exclusive scan -> row_ptr & cursor; also dinv = rsqrt(deg+1)  (self-loop)
__global__ __launch_bounds__(256) void k_scan_out(const int* __restrict__ deg,
                                                  const int* __restrict__ bsum,
                                                  int* __restrict__ row_ptr,
                                                  int* __restrict__ cursor,
                                                  float* __restrict__ dinv) {
    __shared__ int s[256];
    int tid = threadIdx.x;
    int base = blockIdx.x * SCAN_BLK + tid * 4;
    int v[4]; int t = 0;
    for (int j = 0; j < 4; ++j) { int i = base + j; v[j] = (i < N_NODES) ? deg[i] : 0; t += v[j]; }
    s[tid] = t; __syncthreads();
    if (tid == 0) { int acc = 0; for (int k = 0; k < 256; ++k) { int tv = s[k]; s[k] = acc; acc += tv; } }
    __syncthreads();
    int off = bsum[blockIdx.x] + s[tid];
    for (int j = 0; j < 4; ++j) {
        int i = base + j;
        if (i < N_NODES) {
            row_ptr[i] = off; cursor[i] = off; off += v[j];
            dinv[i] = rsqrtf((float)v[j] + 1.0f);
        }
    }
}

__global__ void k_sortsrc(const int* __restrict__ src, const int* __restrict__ dst,
                          int* __restrict__ cursor, int* __restrict__ sorted_src) {
    int e = blockIdx.x * blockDim.x + threadIdx.x;
    if (e >= N_EDGES) return;
    int pos = atomicAdd(&cursor[dst[e]], 1);
    sorted_src[pos] = src[e];
}

// ---------------- feature pipeline ----------------

// table[t][j] = sum_k emb[t][k] * W1[k][j]   (200 x 32)
__global__ void k_table(const float* __restrict__ emb, const float* __restrict__ W1,
                        float* __restrict__ table) {
    int i = blockIdx.x * blockDim.x + threadIdx.x;
    if (i >= NUM_TYPES * HID) return;
    int t = i / HID, j = i % HID;
    float s = 0.f;
    for (int k = 0; k < EMB; ++k) s = fmaf(emb[t * EMB + k], W1[k * HID + j], s);
    table[i] = s;
}

// Y[i] = table[ids[i]] * dinv[i]
__global__ void k_y1(const int* __restrict__ ids, const float* __restrict__ table,
                     const float* __restrict__ dinv, float4* __restrict__ Y) {
    int t = blockIdx.x * blockDim.x + threadIdx.x;
    if (t >= N_NODES * 8) return;
    int i = t >> 3, p = t & 7;
    float d = dinv[i];
    int id = ids[i];
    float4 v = ((const float4*)table)[id * 8 + p];
    v.x *= d; v.y *= d; v.z *= d; v.w *= d;
    Y[i * 8 + p] = v;
}

// H[i] = relu(dinv[i] * (Y[i] + sum_{s->i} Y[s]) + b)   -- 8 lanes per node
__global__ void k_gather(const float4* __restrict__ Y, const int* __restrict__ row_ptr,
                         const int* __restrict__ deg, const int* __restrict__ sorted_src,
                         const float* __restrict__ dinv, const float* __restrict__ b,
                         float4* __restrict__ H) {
    int t = blockIdx.x * blockDim.x + threadIdx.x;
    if (t >= N_NODES * 8) return;
    int i = t >> 3, p = t & 7;
    float4 acc = Y[i * 8 + p];                 // self-loop term
    int s0 = row_ptr[i], n = deg[i];
    for (int e = 0; e < n; ++e) {
        int s = sorted_src[s0 + e];
        float4 v = Y[s * 8 + p];
        acc.x += v.x; acc.y += v.y; acc.z += v.z; acc.w += v.w;
    }
    float d = dinv[i];
    float4 bb = ((const float4*)b)[p];
    float4 h;
    h.x = fmaxf(fmaf(d, acc.x, bb.x), 0.f);
    h.y = fmaxf(fmaf(d, acc.y, bb.y), 0.f);
    h.z = fmaxf(fmaf(d, acc.z, bb.z), 0.f);
    h.w = fmaxf(fmaf(d, acc.w, bb.w), 0.f);
    H[i * 8 + p] = h;
}

// Y[i] = (H[i] @ W2) * dinv[i]   (one node per thread, W2 in LDS)
__global__ __launch_bounds__(256) void k_y2(const float* __restrict__ H,
                                            const float* __restrict__ W2,
                                            const float* __restrict__ dinv,
                                            float* __restrict__ Y) {
    __shared__ float w[HID * HID];
    for (int k = threadIdx.x; k < HID * HID; k += blockDim.x) w[k] = W2[k];
    __syncthreads();
    int i = blockIdx.x * blockDim.x + threadIdx.x;
    if (i >= N_NODES) return;
    float h[HID];
    const float4* hp = (const float4*)(H + (size_t)i * HID);
    for (int q = 0; q < 8; ++q) {
        float4 v = hp[q];
        h[q * 4 + 0] = v.x; h[q * 4 + 1] = v.y; h[q * 4 + 2] = v.z; h[q * 4 + 3] = v.w;
    }
    float out[HID];
#pragma unroll
    for (int j = 0; j < HID; ++j) out[j] = 0.f;
    for (int k = 0; k < HID; ++k) {
        float hk = h[k];
#pragma unroll
        for (int j = 0; j < HID; ++j) out[j] = fmaf(hk, w[k * HID + j], out[j]);
    }
    float d = dinv[i];
    float4* yp = (float4*)(Y + (size_t)i * HID);
    for (int q = 0; q < 8; ++q) {
        float4 v;
        v.x = out[q * 4 + 0] * d; v.y = out[q * 4 + 1] * d;
        v.z = out[q * 4 + 2] * d; v.w = out[q * 4 + 3] * d;
        yp[q] = v;
    }
}

// fused mean-pool + MLP head: one block per graph (batch is sorted)
__global__ __launch_bounds__(256) void k_pool_head(
        const float* __restrict__ H, const int* __restrict__ batch,
        const float* __restrict__ Wc1, const float* __restrict__ bc1,
        const float* __restrict__ Wc2, const float* __restrict__ bc2,
        float* __restrict__ out) {
    int g = blockIdx.x;
    int tid = threadIdx.x;
    int p = tid & 31, r = tid >> 5;           // feature, row-group

    // binary search: start = lower_bound(batch, g), end = lower_bound(batch, g+1)
    int lo = 0, hi = N_NODES;
    while (lo < hi) { int mid = (lo + hi) >> 1; if (batch[mid] < g) lo = mid + 1; else hi = mid; }
    int start = lo;
    hi = N_NODES;
    while (lo < hi) { int mid = (lo + hi) >> 1; if (batch[mid] < g + 1) lo = mid + 1; else hi = mid; }
    int end = lo;

    float acc = 0.f;
    for (int i = start + r; i < end; i += 8) acc += H[(size_t)i * HID + p];

    __shared__ float s[8][HID];
    s[r][p] = acc; __syncthreads();
    if (r < 4) s[r][p] += s[r + 4][p]; __syncthreads();
    if (r < 2) s[r][p] += s[r + 2][p]; __syncthreads();

    __shared__ float m[HID];
    __shared__ float hc[16];
    if (r == 0) {
        float inv = 1.0f / fmaxf((float)(end - start), 1.0f);
        m[p] = (s[0][p] + s[1][p]) * inv;
    }
    __syncthreads();
    if (tid < 16) {
        float sj = bc1[tid];
        for (int k = 0; k < HID; ++k) sj = fmaf(m[k], Wc1[k * 16 + tid], sj);
        hc[tid] = fmaxf(sj, 0.f);
    }
    __syncthreads();
    if (tid == 0) {
        float sv = bc2[0];
        for (int k = 0; k < 16; ++k) sv = fmaf(hc[k], Wc2[k], sv);
        out[g] = 1.0f / (1.0f + expf(-sv));
    }
}

// ---------------- launch ----------------

extern "C" void kernel_launch(void* const* d_in, const int* in_sizes, int n_in,
                              void* d_out, int out_size, void* d_ws, size_t ws_size,
                              hipStream_t stream) {
    const int*   ids  = (const int*)d_in[0];
    const int*   src  = (const int*)d_in[1];
    const int*   dst  = ((const int*)d_in[1]) + N_EDGES;
    const int*   batch = (const int*)d_in[2];
    const float* emb  = (const float*)d_in[3];
    const float* W1   = (const float*)d_in[4];
    const float* b1   = (const float*)d_in[5];
    const float* W2   = (const float*)d_in[6];
    const float* b2   = (const float*)d_in[7];
    const float* Wc1  = (const float*)d_in[8];
    const float* bc1  = (const float*)d_in[9];
    const float* Wc2  = (const float*)d_in[10];
    const float* bc2  = (const float*)d_in[11];
    float* out = (float*)d_out;

    // workspace layout
    int* deg      = (int*)d_ws;                 // 100000
    int* row_ptr  = deg + N_NODES;              // 100000
    int* cursor   = row_ptr + N_NODES;          // 100000
    int* bsum     = cursor + N_NODES;           // 128
    int* ssrc     = bsum + 128;                 // 1,000,000
    float* dinv   = (float*)(ssrc + N_EDGES);   // 100000
    float* table  = dinv + N_NODES;             // 6400
    float* Y      = table + NUM_TYPES * HID;    // 3,200,000 (16B-aligned)
    float* H      = Y + (size_t)N_NODES * HID;  // 3,200,000

    const int B = 256;
    const int gNodes = (N_NODES + B - 1) / B;
    const int gNode8 = (N_NODES * 8 + B - 1) / B;
    const int gEdges = (N_EDGES + B - 1) / B;

    // CSR build + dinv
    hipMemsetAsync(deg, 0, N_NODES * sizeof(int), stream);
    k_hist<<<gEdges, B, 0, stream>>>(dst, deg);
    k_scan_bsum<<<NSCAN, B, 0, stream>>>(deg, bsum);
    k_scan_top<<<1, 64, 0, stream>>>(bsum);
    k_scan_out<<<NSCAN, B, 0, stream>>>(deg, bsum, row_ptr, cursor, dinv);
    k_sortsrc<<<gEdges, B, 0, stream>>>(src, dst, cursor, ssrc);

    // layer-1 table (emb @ W1, 200x32)
    k_table<<<(NUM_TYPES * HID + B - 1) / B, B, 0, stream>>>(emb, W1, table);

    // layer 1
    k_y1<<<gNode8, B, 0, stream>>>(ids, table, dinv, (float4*)Y);
    k_gather<<<gNode8, B, 0, stream>>>((const float4*)Y, row_ptr, deg, ssrc, dinv, b1, (float4*)H);

    // layer 2
    k_y2<<<gNodes, B, 0, stream>>>(H, W2, dinv, Y);
    k_gather<<<gNode8, B, 0, stream>>>((const float4*)Y, row_ptr, deg, ssrc, dinv, b2, (float4*)H);

    // fused pooling + head (one block per graph; batch is sorted)
    k_pool_head<<<N_GRAPHS, B, 0, stream>>>(H, batch, Wc1, bc1, Wc2, bc2, out);
}

// Round 4
// 218.780 us; speedup vs baseline: 5.2896x; 1.0660x over previous
//
#include <hip/hip_runtime.h>
#include <math.h>

#define N_NODES   100000
#define N_EDGES   1000000
#define N_GRAPHS  256
#define NUM_TYPES 200
#define EMB       64
#define HID       32
#define SCAN_BLK  1024
#define NSCAN     ((N_NODES + SCAN_BLK - 1) / SCAN_BLK)   // 98 blocks

// ---------------- CSR build ----------------

__global__ void k_hist(const int* __restrict__ dst, int* __restrict__ deg) {
    int e = blockIdx.x * blockDim.x + threadIdx.x;
    if (e < N_EDGES) atomicAdd(&deg[dst[e]], 1);
}

__global__ __launch_bounds__(256) void k_scan_bsum(const int* __restrict__ deg,
                                                   int* __restrict__ bsum) {
    __shared__ int s[256];
    int tid = threadIdx.x;
    int base = blockIdx.x * SCAN_BLK + tid * 4;
    int t = 0;
    for (int j = 0; j < 4; ++j) { int i = base + j; if (i < N_NODES) t += deg[i]; }
    s[tid] = t; __syncthreads();
    for (int off = 128; off > 0; off >>= 1) {
        if (tid < off) s[tid] += s[tid + off];
        __syncthreads();
    }
    if (tid == 0) bsum[blockIdx.x] = s[0];
}

__global__ void k_scan_top(int* __restrict__ bsum) {
    if (threadIdx.x == 0) {
        int acc = 0;
        for (int b = 0; b < NSCAN; ++b) { int v = bsum[b]; bsum[b] = acc; acc += v; }
    }
}

// exclusive scan -> row_ptr & cursor; also dinv = rsqrt(deg+1)  (self-loop)
__global__ __launch_bounds__(256) void k_scan_out(const int* __restrict__ deg,
                                                  const int* __restrict__ bsum,
                                                  int* __restrict__ row_ptr,
                                                  int* __restrict__ cursor,
                                                  float* __restrict__ dinv) {
    __shared__ int s[256];
    int tid = threadIdx.x;
    int base = blockIdx.x * SCAN_BLK + tid * 4;
    int v[4]; int t = 0;
    for (int j = 0; j < 4; ++j) { int i = base + j; v[j] = (i < N_NODES) ? deg[i] : 0; t += v[j]; }
    s[tid] = t; __syncthreads();
    if (tid == 0) { int acc = 0; for (int k = 0; k < 256; ++k) { int tv = s[k]; s[k] = acc; acc += tv; } }
    __syncthreads();
    int off = bsum[blockIdx.x] + s[tid];
    for (int j = 0; j < 4; ++j) {
        int i = base + j;
        if (i < N_NODES) {
            row_ptr[i] = off; cursor[i] = off; off += v[j];
            dinv[i] = rsqrtf((float)v[j] + 1.0f);
        }
    }
}

__global__ void k_sortsrc(const int* __restrict__ src, const int* __restrict__ dst,
                          int* __restrict__ cursor, int* __restrict__ sorted_src) {
    int e = blockIdx.x * blockDim.x + threadIdx.x;
    if (e >= N_EDGES) return;
    int pos = atomicAdd(&cursor[dst[e]], 1);
    sorted_src[pos] = src[e];
}

// ---------------- feature pipeline ----------------

// table[t][j] = sum_k emb[t][k] * W1[k][j]   (200 x 32)
__global__ void k_table(const float* __restrict__ emb, const float* __restrict__ W1,
                        float* __restrict__ table) {
    int i = blockIdx.x * blockDim.x + threadIdx.x;
    if (i >= NUM_TYPES * HID) return;
    int t = i / HID, j = i % HID;
    float s = 0.f;
    for (int k = 0; k < EMB; ++k) s = fmaf(emb[t * EMB + k], W1[k * HID + j], s);
    table[i] = s;
}

// Layer 1 + layer-2 producer, fully fused:
//   h1[i]  = relu(dinv[i]*(sum_{s in {i} u N(i)} table[ids[s]]*dinv[s]) + b1)
//   Y2[i]  = (h1[i] @ W2) * dinv[i]
// 8 lanes per node; W2 GEMM via intra-8-lane shuffles, W2 in LDS.
__global__ __launch_bounds__(256) void k_gather1(
        const int* __restrict__ ids, const float* __restrict__ table,
        const int* __restrict__ row_ptr, const int* __restrict__ deg,
        const int* __restrict__ ssrc, const float* __restrict__ dinv,
        const float* __restrict__ b1, const float* __restrict__ W2,
        float4* __restrict__ Y2) {
    __shared__ float w[HID * HID];
    for (int k = threadIdx.x; k < HID * HID; k += blockDim.x) w[k] = W2[k];
    __syncthreads();

    int t = blockIdx.x * blockDim.x + threadIdx.x;   // grid is exact: 800000 threads
    int i = t >> 3, p = t & 7;
    const float4* tab4 = (const float4*)table;

    float di = dinv[i];
    float4 acc = tab4[ids[i] * 8 + p];               // self term
    acc.x *= di; acc.y *= di; acc.z *= di; acc.w *= di;

    int s0 = row_ptr[i], n = deg[i];
    for (int e = 0; e < n; ++e) {
        int s = ssrc[s0 + e];
        float ds = dinv[s];
        float4 v = tab4[ids[s] * 8 + p];
        acc.x = fmaf(v.x, ds, acc.x);
        acc.y = fmaf(v.y, ds, acc.y);
        acc.z = fmaf(v.z, ds, acc.z);
        acc.w = fmaf(v.w, ds, acc.w);
    }
    float4 bb = ((const float4*)b1)[p];
    float4 h;
    h.x = fmaxf(fmaf(di, acc.x, bb.x), 0.f);
    h.y = fmaxf(fmaf(di, acc.y, bb.y), 0.f);
    h.z = fmaxf(fmaf(di, acc.z, bb.z), 0.f);
    h.w = fmaxf(fmaf(di, acc.w, bb.w), 0.f);

    // out[4p+c] = sum_k h[k] * W2[k][4p+c]
    float o0 = 0.f, o1 = 0.f, o2 = 0.f, o3 = 0.f;
    const float4* w4 = (const float4*)w;
#pragma unroll
    for (int q = 0; q < 8; ++q) {
        float4 hq;
        hq.x = __shfl(h.x, q, 8);
        hq.y = __shfl(h.y, q, 8);
        hq.z = __shfl(h.z, q, 8);
        hq.w = __shfl(h.w, q, 8);
        float4 w0 = w4[(4 * q + 0) * 8 + p];
        float4 w1 = w4[(4 * q + 1) * 8 + p];
        float4 w2 = w4[(4 * q + 2) * 8 + p];
        float4 w3 = w4[(4 * q + 3) * 8 + p];
        o0 = fmaf(hq.x, w0.x, o0); o1 = fmaf(hq.x, w0.y, o1); o2 = fmaf(hq.x, w0.z, o2); o3 = fmaf(hq.x, w0.w, o3);
        o0 = fmaf(hq.y, w1.x, o0); o1 = fmaf(hq.y, w1.y, o1); o2 = fmaf(hq.y, w1.z, o2); o3 = fmaf(hq.y, w1.w, o3);
        o0 = fmaf(hq.z, w2.x, o0); o1 = fmaf(hq.z, w2.y, o1); o2 = fmaf(hq.z, w2.z, o2); o3 = fmaf(hq.z, w2.w, o3);
        o0 = fmaf(hq.w, w3.x, o0); o1 = fmaf(hq.w, w3.y, o1); o2 = fmaf(hq.w, w3.z, o2); o3 = fmaf(hq.w, w3.w, o3);
    }
    float4 yv;
    yv.x = o0 * di; yv.y = o1 * di; yv.z = o2 * di; yv.w = o3 * di;
    Y2[i * 8 + p] = yv;
}

// Layer 2 + fused mean-pool partial sums (batch is sorted):
//   h2[i] = relu(dinv[i]*(Y2[i] + sum Y2[s]) + b2);  pooled[batch[i]] += h2[i]
__global__ __launch_bounds__(256) void k_gather2(
        const float4* __restrict__ Y2, const int* __restrict__ row_ptr,
        const int* __restrict__ deg, const int* __restrict__ ssrc,
        const float* __restrict__ dinv, const float* __restrict__ b2,
        const int* __restrict__ batch, float* __restrict__ pooled) {
    __shared__ float lp[32][HID];                    // per-block per-graph partials
    for (int k = threadIdx.x; k < 32 * HID; k += blockDim.x) ((float*)lp)[k] = 0.f;
    __syncthreads();

    int t = blockIdx.x * blockDim.x + threadIdx.x;
    int i = t >> 3, p = t & 7;
    int i0 = (blockIdx.x * blockDim.x) >> 3;         // first node of block
    int gFirst = batch[i0];

    float4 acc = Y2[i * 8 + p];                      // self term
    int s0 = row_ptr[i], n = deg[i];
    for (int e = 0; e < n; ++e) {
        int s = ssrc[s0 + e];
        float4 v = Y2[s * 8 + p];
        acc.x += v.x; acc.y += v.y; acc.z += v.z; acc.w += v.w;
    }
    float di = dinv[i];
    float4 bb = ((const float4*)b2)[p];
    float4 h;
    h.x = fmaxf(fmaf(di, acc.x, bb.x), 0.f);
    h.y = fmaxf(fmaf(di, acc.y, bb.y), 0.f);
    h.z = fmaxf(fmaf(di, acc.z, bb.z), 0.f);
    h.w = fmaxf(fmaf(di, acc.w, bb.w), 0.f);

    int gl = batch[i] - gFirst;                      // 0..31 within block
    atomicAdd(&lp[gl][p * 4 + 0], h.x);
    atomicAdd(&lp[gl][p * 4 + 1], h.y);
    atomicAdd(&lp[gl][p * 4 + 2], h.z);
    atomicAdd(&lp[gl][p * 4 + 3], h.w);
    __syncthreads();

    int gLast = batch[i0 + 31];
    int ng = gLast - gFirst + 1;
    for (int k = threadIdx.x; k < ng * HID; k += blockDim.x) {
        float v = lp[k / HID][k % HID];
        if (v != 0.f) atomicAdd(&pooled[(gFirst + k / HID) * HID + (k % HID)], v);
    }
}

// head: mean (counts via binary search) -> relu(@Wc1+bc1) -> sigmoid(@Wc2+bc2)
__global__ void k_head(const float* __restrict__ pooled, const int* __restrict__ batch,
                       const float* __restrict__ Wc1, const float* __restrict__ bc1,
                       const float* __restrict__ Wc2, const float* __restrict__ bc2,
                       float* __restrict__ out) {
    int g = blockIdx.x * blockDim.x + threadIdx.x;
    if (g >= N_GRAPHS) return;
    int lo = 0, hi = N_NODES;
    while (lo < hi) { int mid = (lo + hi) >> 1; if (batch[mid] < g) lo = mid + 1; else hi = mid; }
    int start = lo;
    hi = N_NODES;
    while (lo < hi) { int mid = (lo + hi) >> 1; if (batch[mid] < g + 1) lo = mid + 1; else hi = mid; }
    int end = lo;
    float inv = 1.0f / fmaxf((float)(end - start), 1.0f);
    float m[HID];
    for (int j = 0; j < HID; ++j) m[j] = pooled[g * HID + j] * inv;
    float hc[16];
    for (int j = 0; j < 16; ++j) {
        float s = bc1[j];
        for (int k = 0; k < HID; ++k) s = fmaf(m[k], Wc1[k * 16 + j], s);
        hc[j] = fmaxf(s, 0.f);
    }
    float s = bc2[0];
    for (int k = 0; k < 16; ++k) s = fmaf(hc[k], Wc2[k], s);
    out[g] = 1.0f / (1.0f + expf(-s));
}

// ---------------- launch ----------------

extern "C" void kernel_launch(void* const* d_in, const int* in_sizes, int n_in,
                              void* d_out, int out_size, void* d_ws, size_t ws_size,
                              hipStream_t stream) {
    const int*   ids  = (const int*)d_in[0];
    const int*   src  = (const int*)d_in[1];
    const int*   dst  = ((const int*)d_in[1]) + N_EDGES;
    const int*   batch = (const int*)d_in[2];
    const float* emb  = (const float*)d_in[3];
    const float* W1   = (const float*)d_in[4];
    const float* b1   = (const float*)d_in[5];
    const float* W2   = (const float*)d_in[6];
    const float* b2   = (const float*)d_in[7];
    const float* Wc1  = (const float*)d_in[8];
    const float* bc1  = (const float*)d_in[9];
    const float* Wc2  = (const float*)d_in[10];
    const float* bc2  = (const float*)d_in[11];
    float* out = (float*)d_out;

    // workspace layout
    int* deg      = (int*)d_ws;                 // 100000
    int* row_ptr  = deg + N_NODES;              // 100000
    int* cursor   = row_ptr + N_NODES;          // 100000
    int* bsum     = cursor + N_NODES;           // 128
    int* ssrc     = bsum + 128;                 // 1,000,000
    float* dinv   = (float*)(ssrc + N_EDGES);   // 100000
    float* table  = dinv + N_NODES;             // 6400 (16B-aligned: offsets all x4)
    float* Y2     = table + NUM_TYPES * HID;    // 3,200,000
    float* pooled = Y2 + (size_t)N_NODES * HID; // 8192

    const int B = 256;
    const int gNode8 = (N_NODES * 8) / B;       // exact: 3125
    const int gEdges = (N_EDGES + B - 1) / B;

    hipMemsetAsync(deg, 0, N_NODES * sizeof(int), stream);
    hipMemsetAsync(pooled, 0, N_GRAPHS * HID * sizeof(float), stream);

    // CSR build + dinv
    k_hist<<<gEdges, B, 0, stream>>>(dst, deg);
    k_scan_bsum<<<NSCAN, B, 0, stream>>>(deg, bsum);
    k_scan_top<<<1, 64, 0, stream>>>(bsum);
    k_scan_out<<<NSCAN, B, 0, stream>>>(deg, bsum, row_ptr, cursor, dinv);
    k_sortsrc<<<gEdges, B, 0, stream>>>(src, dst, cursor, ssrc);

    // layer-1 table (emb @ W1, 200x32)
    k_table<<<(NUM_TYPES * HID + B - 1) / B, B, 0, stream>>>(emb, W1, table);

    // fused layer1 + W2 producer
    k_gather1<<<gNode8, B, 0, stream>>>(ids, table, row_ptr, deg, ssrc, dinv, b1, W2,
                                        (float4*)Y2);
    // fused layer2 + pooling
    k_gather2<<<gNode8, B, 0, stream>>>((const float4*)Y2, row_ptr, deg, ssrc, dinv, b2,
                                        batch, pooled);
    // head
    k_head<<<1, N_GRAPHS, 0, stream>>>(pooled, batch, Wc1, bc1, Wc2, bc2, out);
}